// Round 10
// baseline (2042.887 us; speedup 1.0000x reference)
//
#include <hip/hip_runtime.h>
#include <hip/hip_bf16.h>
#include <stdint.h>

#define VOCAB 32000
#define HID 512
#define NB 8
#define SEQ 512
#define NG 1536
#define LN_EPS 1e-5f
#define GRU_WGS 32
#define NWRK 224
#define TW 16
#define NTW (SEQ / TW)     // 32 windows
#define NBN (VOCAB / 128)  // 250 vocab tiles
#define GRU_SPIN_BUDGET (1 << 20)
#define WRK_SPIN_BUDGET (1 << 22)

typedef short bf16x8 __attribute__((ext_vector_type(8)));
typedef float f32x4 __attribute__((ext_vector_type(4)));

__device__ __forceinline__ unsigned short f2bf(float f) {
  union { float f; uint32_t u; } c; c.f = f;
  return (unsigned short)((c.u + 0x7fffu + ((c.u >> 16) & 1u)) >> 16);
}

// ---------------- init workspace ---------------------------------------------
// ibase: [0..511]=flags, [512..1023]=gflags, [1024..1535]=wflag (all x16
// strided). h_state = 2 x [16][HID] bf16 zeros.
__global__ void init_ws_kernel(int* ibase, unsigned short* h_state) {
  int i = blockIdx.x * 256 + threadIdx.x;
  if (i < 1536) ibase[i] = 0;
  if (i < 2 * 16 * HID) h_state[i] = 0;
}

// ---------------- fp32 -> bf16 bulk convert ---------------------------------
__global__ void conv_bf16_kernel(const float* __restrict__ in,
                                 unsigned short* __restrict__ out, int n4) {
  int i = blockIdx.x * 256 + threadIdx.x;
  if (i >= n4) return;
  const float4 v = ((const float4*)in)[i];
  ushort4 o;
  o.x = f2bf(v.x); o.y = f2bf(v.y); o.z = f2bf(v.z); o.w = f2bf(v.w);
  ((ushort4*)out)[i] = o;
}

// ---------------- embedding gather -> bf16 A matrix [4096][512] -------------
__global__ void embed_kernel(const int* __restrict__ ids,
                             const float* __restrict__ emb,
                             unsigned short* __restrict__ out) {
  int row = blockIdx.x;
  int id = ids[row];
  int c = threadIdx.x * 2;
  const float2 v = *(const float2*)(emb + (size_t)id * HID + c);
  ushort2 o; o.x = f2bf(v.x); o.y = f2bf(v.y);
  *(ushort2*)(out + (size_t)row * HID + c) = o;
}

// ---------------- bf16 GEMM: C = A * B^T + bias (xg GEMM) -------------------
#define BM 128
#define BN 128
#define BK 32

__global__ __launch_bounds__(256, 2) void gemm_bt_kernel(
    const unsigned short* __restrict__ A, const unsigned short* __restrict__ B,
    const float* __restrict__ bias, float* __restrict__ C, int N, int nbn) {
  __shared__ unsigned short a_lds[BM * BK];
  __shared__ unsigned short b_lds[BN * BK];
  const int nwg = gridDim.x;
  const int chunk = nwg >> 3;
  const int bid = blockIdx.x;
  const int sw = (bid & 7) * chunk + (bid >> 3);
  const int bm = sw / nbn, bn = sw % nbn;
  const int tid = threadIdx.x;
  const int lane = tid & 63, wid = tid >> 6;
  const int wm = wid >> 1, wn = wid & 1;

  f32x4 acc[4][4] = {};

  for (int kt = 0; kt < HID / BK; ++kt) {
    __syncthreads();
#pragma unroll
    for (int p = 0; p < 2; ++p) {
      const int flat = (p * 256 + tid) * 16;
      const int row = flat >> 6;
      const int kb = flat & 63;
      const char* ga =
          (const char*)(A + ((size_t)(bm * BM + row) * HID + kt * BK)) + kb;
      const char* gb =
          (const char*)(B + ((size_t)(bn * BN + row) * HID + kt * BK)) + kb;
      char* la = (char*)a_lds + (size_t)(p * 256 + wid * 64) * 16;
      char* lb = (char*)b_lds + (size_t)(p * 256 + wid * 64) * 16;
      __builtin_amdgcn_global_load_lds(
          (const __attribute__((address_space(1))) void*)ga,
          (__attribute__((address_space(3))) void*)la, 16, 0, 0);
      __builtin_amdgcn_global_load_lds(
          (const __attribute__((address_space(1))) void*)gb,
          (__attribute__((address_space(3))) void*)lb, 16, 0, 0);
    }
    __syncthreads();
    bf16x8 af[4], bfr[4];
#pragma unroll
    for (int i = 0; i < 4; ++i) {
      af[i] = *(const bf16x8*)(a_lds + (wm * 64 + i * 16 + (lane & 15)) * BK +
                               (lane >> 4) * 8);
      bfr[i] = *(const bf16x8*)(b_lds + (wn * 64 + i * 16 + (lane & 15)) * BK +
                                (lane >> 4) * 8);
    }
#pragma unroll
    for (int i = 0; i < 4; ++i)
#pragma unroll
      for (int j = 0; j < 4; ++j)
        acc[i][j] =
            __builtin_amdgcn_mfma_f32_16x16x32_bf16(af[i], bfr[j], acc[i][j], 0, 0, 0);
  }
#pragma unroll
  for (int i = 0; i < 4; ++i) {
    const int mrow = bm * BM + wm * 64 + i * 16 + (lane >> 4) * 4;
#pragma unroll
    for (int j = 0; j < 4; ++j) {
      const int col = bn * BN + wn * 64 + j * 16 + (lane & 15);
      const float bv = bias[col];
#pragma unroll
      for (int r = 0; r < 4; ++r)
        C[(size_t)(mrow + r) * N + col] = acc[i][j][r] + bv;
    }
  }
}

// ---------------- fused persistent mega-kernel -------------------------------
// Blocks 0..31: VERBATIM round-5 GRU (1 wave, flag protocol, agent-scope=LLC,
//   placement-independent). Additions: hs stores agent-scope (off critical
//   path, drained by the NEXT step's vmcnt(0)); gflags=t published at steps
//   t%TW==0 after that drain (covers hs of steps < t), final gflags=SEQ after
//   the loop. Zero new ops on the per-step critical path.
// Blocks 32..255: lean workers. First 32 do LN once for their window
//   (hs fp32 agent-read -> bf16 yb agent-write -> wflag). All 224 then loop
//   vocab tiles: A-frags DIRECT from yb (plain loads; lines first touched
//   after wflag so no staleness), B via global_load_lds, logits nontemporal.
__global__ __launch_bounds__(256, 1) void mega_kernel(
    const float* __restrict__ xg, const float* __restrict__ w_hh,
    const float* __restrict__ b_hh, float* __restrict__ hs,
    unsigned short* __restrict__ h_state, int* __restrict__ ibase,
    const unsigned short* __restrict__ hwb, const float* __restrict__ head_b,
    const float* __restrict__ gamma, const float* __restrict__ beta,
    unsigned short* __restrict__ yb, float* __restrict__ out) {
  int* flags = ibase;           // GRU step flags (agent/LLC)
  int* gflags = ibase + 512;    // windowed GRU progress (agent/LLC)
  int* wflag = ibase + 1024;    // per-window yb-ready

  __shared__ float h_pub[8][16];
  __shared__ unsigned short b_lds[128 * 32];
  __shared__ float st_s[256], st_q[256];
  __shared__ float mu_lds[128], is_lds[128];

  const int tid = threadIdx.x;

  if (blockIdx.x < GRU_WGS) {
    // =================== GRU path (round-5 verbatim + gflags) ===============
    if (tid >= 64) return;
    const int wid = blockIdx.x;
    const int lane = tid;
    const int col16 = lane & 15;
    const int kq = lane >> 4;

    bf16x8 wf[3][16];
#pragma unroll
    for (int g = 0; g < 3; ++g) {
      const float* wr =
          w_hh + (size_t)(g * HID + wid * 16 + col16) * HID + kq * 8;
#pragma unroll
      for (int kk = 0; kk < 16; ++kk) {
        float4 f0 = *(const float4*)(wr + kk * 32);
        float4 f1 = *(const float4*)(wr + kk * 32 + 4);
        bf16x8 v;
        v[0] = (short)f2bf(f0.x); v[1] = (short)f2bf(f0.y);
        v[2] = (short)f2bf(f0.z); v[3] = (short)f2bf(f0.w);
        v[4] = (short)f2bf(f1.x); v[5] = (short)f2bf(f1.y);
        v[6] = (short)f2bf(f1.z); v[7] = (short)f2bf(f1.w);
        wf[g][kk] = v;
      }
    }
    const float bh_r = b_hh[0 * HID + wid * 16 + col16];
    const float bh_z = b_hh[1 * HID + wid * 16 + col16];
    const float bh_n = b_hh[2 * HID + wid * 16 + col16];

    const int abase = col16 * HID + kq * 8;
    const bool realrow = col16 < 8;
    const bool owner = lane < 32;
    const int bbase = kq * 4;

    float xr[4], xz[4], xn[4];
#pragma unroll
    for (int r = 0; r < 4; ++r) { xr[r] = 0.f; xz[r] = 0.f; xn[r] = 0.f; }
    if (owner) {
#pragma unroll
      for (int r = 0; r < 4; ++r) {
        const size_t xo = (size_t)(bbase + r) * SEQ * NG + wid * 16 + col16;
        xr[r] = xg[xo];
        xz[r] = xg[xo + HID];
        xn[r] = xg[xo + 2 * HID];
      }
    }
    float hprev[4] = {0.f, 0.f, 0.f, 0.f};
    int budget = GRU_SPIN_BUDGET;

    for (int t = 0; t < SEQ; ++t) {
      // ---- wait for h_t (flags >= t) ----
      while (budget > 0) {
        int v = t;
        if (lane < 32)
          v = __hip_atomic_load(flags + lane * 16, __ATOMIC_RELAXED,
                                __HIP_MEMORY_SCOPE_AGENT);
        if (__ballot(v >= t) == ~0ULL) break;
        --budget;
        __builtin_amdgcn_s_sleep(1);
      }

      const unsigned short* rd = h_state + (size_t)(t & 1) * (16 * HID);
      unsigned short* wpub = h_state + (size_t)((t + 1) & 1) * (16 * HID);

      // ---- bulk-load A fragments (one shot, all independent) ----
      uint64_t hb[32];
#pragma unroll
      for (int kk = 0; kk < 32; ++kk) hb[kk] = 0;
      if (realrow) {
#pragma unroll
        for (int kk = 0; kk < 16; ++kk) {
          const uint64_t* ap = (const uint64_t*)(rd + abase + kk * 32);
          hb[2 * kk] = __hip_atomic_load(ap, __ATOMIC_RELAXED,
                                         __HIP_MEMORY_SCOPE_AGENT);
          hb[2 * kk + 1] = __hip_atomic_load(ap + 1, __ATOMIC_RELAXED,
                                             __HIP_MEMORY_SCOPE_AGENT);
        }
      }

      // ---- three independent 16-deep MFMA chains (r, z, n) ----
      f32x4 ar = {0.f, 0.f, 0.f, 0.f};
      f32x4 az = {0.f, 0.f, 0.f, 0.f};
      f32x4 an = {0.f, 0.f, 0.f, 0.f};
#pragma unroll
      for (int kk = 0; kk < 16; ++kk) {
        union { uint64_t u[2]; bf16x8 v; } cv;
        cv.u[0] = hb[2 * kk]; cv.u[1] = hb[2 * kk + 1];
        ar = __builtin_amdgcn_mfma_f32_16x16x32_bf16(cv.v, wf[0][kk], ar, 0, 0, 0);
        az = __builtin_amdgcn_mfma_f32_16x16x32_bf16(cv.v, wf[1][kk], az, 0, 0, 0);
        an = __builtin_amdgcn_mfma_f32_16x16x32_bf16(cv.v, wf[2][kk], an, 0, 0, 0);
      }

      // ---- in-register gate math ----
      float hnew[4] = {0.f, 0.f, 0.f, 0.f};
      if (owner) {
#pragma unroll
        for (int r = 0; r < 4; ++r) {
          const float rg = 1.f / (1.f + __expf(-(xr[r] + ar[r] + bh_r)));
          const float zg = 1.f / (1.f + __expf(-(xz[r] + az[r] + bh_z)));
          const float a = xn[r] + rg * (an[r] + bh_n);
          const float e2 = __expf(-2.f * fabsf(a));
          const float nn = copysignf((1.f - e2) / (1.f + e2), a);
          hnew[r] = (1.f - zg) * nn + zg * hprev[r];
          hprev[r] = hnew[r];
          h_pub[bbase + r][col16] = hnew[r];
        }
      }
      asm volatile("s_waitcnt lgkmcnt(0)" ::: "memory");
      __builtin_amdgcn_sched_barrier(0);
      // ---- barrier-free within-wave transpose + publish ----
      {
        const int tb = lane >> 3;
        const int tc = (lane & 7) * 2;
        const float2 hp = *(const float2*)&h_pub[tb][tc];
        union { unsigned short s[2]; uint32_t u; } pk;
        pk.s[0] = f2bf(hp.x);
        pk.s[1] = f2bf(hp.y);
        uint32_t* dst = (uint32_t*)(wpub + tb * HID + wid * 16 + tc);
        __hip_atomic_store(dst, pk.u, __ATOMIC_RELAXED,
                           __HIP_MEMORY_SCOPE_AGENT);
      }
      asm volatile("s_waitcnt vmcnt(0)" ::: "memory");  // drain publish stores
      if (lane == 0) {
        __hip_atomic_store(flags + wid * 16, t + 1, __ATOMIC_RELAXED,
                           __HIP_MEMORY_SCOPE_AGENT);
        // window progress: at t%TW==0 the drain above also covered all hs
        // stores of steps < t (issued in earlier iterations)
        if ((t & (TW - 1)) == 0 && t > 0)
          __hip_atomic_store(gflags + wid * 16, t, __ATOMIC_RELAXED,
                             __HIP_MEMORY_SCOPE_AGENT);
      }
      // ---- off-critical-path: hs output (agent) + next xg prefetch ----
      if (owner) {
#pragma unroll
        for (int r = 0; r < 4; ++r) {
          union { float f; uint32_t u; } cv; cv.f = hnew[r];
          __hip_atomic_store(
              (uint32_t*)(hs + ((size_t)(bbase + r) * SEQ + t) * HID +
                          wid * 16 + col16),
              cv.u, __ATOMIC_RELAXED, __HIP_MEMORY_SCOPE_AGENT);
        }
        if (t + 1 < SEQ) {
#pragma unroll
          for (int r = 0; r < 4; ++r) {
            const size_t xo = (size_t)(bbase + r) * SEQ * NG +
                              (size_t)(t + 1) * NG + wid * 16 + col16;
            xr[r] = xg[xo]; xz[r] = xg[xo + HID]; xn[r] = xg[xo + 2 * HID];
          }
        }
      }
    }
    // final window: drain hs stores of steps <= SEQ-1, then publish
    asm volatile("s_waitcnt vmcnt(0)" ::: "memory");
    if (tid == 0)
      __hip_atomic_store(gflags + wid * 16, SEQ, __ATOMIC_RELAXED,
                         __HIP_MEMORY_SCOPE_AGENT);
    return;
  }

  // =================== worker path (blocks 32..255) ==========================
  const int w = blockIdx.x - GRU_WGS;
  const int lane = tid & 63, wv = tid >> 6;

  if (w < NTW) {
    // ---- LN for window w: hs fp32 -> yb bf16 ----
    const int t0 = w * TW;
    const int need = t0 + TW;
    if (tid < 64) {
      int bud = WRK_SPIN_BUDGET;
      for (;;) {
        int v = 0x7fffffff;
        if (lane < 32)
          v = __hip_atomic_load(gflags + lane * 16, __ATOMIC_RELAXED,
                                __HIP_MEMORY_SCOPE_AGENT);
        if (__ballot(v >= need) == ~0ULL || --bud <= 0) break;
        __builtin_amdgcn_s_sleep(8);
      }
    }
    __syncthreads();
    const int row = tid >> 1, half = tid & 1;
    const int grow = (row >> 4) * SEQ + t0 + (row & 15);
    const uint64_t* hp = (const uint64_t*)(hs + (size_t)grow * HID) + half * 128;
    float s = 0.f, q = 0.f;
    for (int j = 0; j < 128; ++j) {
      union { uint64_t u; float f[2]; } cv;
      cv.u = __hip_atomic_load(hp + j, __ATOMIC_RELAXED,
                               __HIP_MEMORY_SCOPE_AGENT);
      s += cv.f[0] + cv.f[1];
      q += cv.f[0] * cv.f[0] + cv.f[1] * cv.f[1];
    }
    st_s[tid] = s; st_q[tid] = q;
    __syncthreads();
    if (tid < 128) {
      const float ss = st_s[2 * tid] + st_s[2 * tid + 1];
      const float qq = st_q[2 * tid] + st_q[2 * tid + 1];
      const float mu = ss * (1.f / 512.f);
      mu_lds[tid] = mu;
      is_lds[tid] = rsqrtf(qq * (1.f / 512.f) - mu * mu + LN_EPS);
    }
    __syncthreads();
    {
      const float mu = mu_lds[row], isv = is_lds[row];
      unsigned short* yp = yb + (size_t)grow * HID + half * 256;
      const float* gp = gamma + half * 256;
      const float* bp = beta + half * 256;
      for (int j = 0; j < 64; ++j) {
        union { uint64_t u; float f[2]; } a0, a1;
        a0.u = __hip_atomic_load(hp + 2 * j, __ATOMIC_RELAXED,
                                 __HIP_MEMORY_SCOPE_AGENT);
        a1.u = __hip_atomic_load(hp + 2 * j + 1, __ATOMIC_RELAXED,
                                 __HIP_MEMORY_SCOPE_AGENT);
        union { unsigned short s4[4]; uint64_t u; } pk;
        pk.s4[0] = f2bf((a0.f[0] - mu) * isv * gp[4 * j + 0] + bp[4 * j + 0]);
        pk.s4[1] = f2bf((a0.f[1] - mu) * isv * gp[4 * j + 1] + bp[4 * j + 1]);
        pk.s4[2] = f2bf((a1.f[0] - mu) * isv * gp[4 * j + 2] + bp[4 * j + 2]);
        pk.s4[3] = f2bf((a1.f[1] - mu) * isv * gp[4 * j + 3] + bp[4 * j + 3]);
        __hip_atomic_store((uint64_t*)(yp + 4 * j), pk.u, __ATOMIC_RELAXED,
                           __HIP_MEMORY_SCOPE_AGENT);
      }
    }
    asm volatile("s_waitcnt vmcnt(0)" ::: "memory");
    __syncthreads();
    if (tid == 0)
      __hip_atomic_store(wflag + w * 16, 1, __ATOMIC_RELAXED,
                         __HIP_MEMORY_SCOPE_AGENT);
  }

  // ---- head-GEMM tiles: [128 window rows] x [128 vocab cols] ----
  for (int ti = w; ti < NTW * NBN; ti += NWRK) {
    const int twi = ti / NBN, bn = ti - twi * NBN;
    const int t0 = twi * TW;
    if (tid == 0) {
      int bud = WRK_SPIN_BUDGET;
      while (__hip_atomic_load(wflag + twi * 16, __ATOMIC_RELAXED,
                               __HIP_MEMORY_SCOPE_AGENT) == 0 &&
             --bud > 0)
        __builtin_amdgcn_s_sleep(16);
    }
    __syncthreads();

    f32x4 acc[2][8] = {};
    for (int kt = 0; kt < 16; ++kt) {
      __syncthreads();
      // B staging: hwb tile via global_load_lds
#pragma unroll
      for (int p = 0; p < 2; ++p) {
        const int flat = (p * 256 + tid) * 16;
        const int brow = flat >> 6;
        const int kb = flat & 63;
        const char* gb =
            (const char*)(hwb + ((size_t)(bn * 128 + brow) * HID + kt * 32)) +
            kb;
        char* lb = (char*)b_lds + (size_t)(p * 256 + wv * 64) * 16;
        __builtin_amdgcn_global_load_lds(
            (const __attribute__((address_space(1))) void*)gb,
            (__attribute__((address_space(3))) void*)lb, 16, 0, 0);
      }
      // A fragments: direct from yb (first touch is post-wflag -> fresh)
      bf16x8 af[2];
#pragma unroll
      for (int i = 0; i < 2; ++i) {
        const int row_l = wv * 32 + i * 16 + (lane & 15);
        const int ga = (row_l >> 4) * SEQ + t0 + (row_l & 15);
        af[i] = *(const bf16x8*)(yb + (size_t)ga * HID + kt * 32 +
                                 (lane >> 4) * 8);
      }
      __syncthreads();
      bf16x8 bfr[8];
#pragma unroll
      for (int j = 0; j < 8; ++j)
        bfr[j] = *(const bf16x8*)(b_lds + (j * 16 + (lane & 15)) * 32 +
                                  (lane >> 4) * 8);
#pragma unroll
      for (int i = 0; i < 2; ++i)
#pragma unroll
        for (int j = 0; j < 8; ++j)
          acc[i][j] = __builtin_amdgcn_mfma_f32_16x16x32_bf16(af[i], bfr[j],
                                                              acc[i][j], 0, 0, 0);
    }
    // epilogue: nontemporal logits
#pragma unroll
    for (int i = 0; i < 2; ++i) {
#pragma unroll
      for (int j = 0; j < 8; ++j) {
        const int col = bn * 128 + j * 16 + (lane & 15);
        const float bv = head_b[col];
#pragma unroll
        for (int r = 0; r < 4; ++r) {
          const int row_l = wv * 32 + i * 16 + (lane >> 4) * 4 + r;
          const int ga = (row_l >> 4) * SEQ + t0 + (row_l & 15);
          __builtin_nontemporal_store(acc[i][j][r] + bv,
                                      &out[(size_t)ga * VOCAB + col]);
        }
      }
    }
  }
}

// ---------------- launch -----------------------------------------------------
extern "C" void kernel_launch(void* const* d_in, const int* in_sizes, int n_in,
                              void* d_out, int out_size, void* d_ws,
                              size_t ws_size, hipStream_t stream) {
  const int* ids = (const int*)d_in[0];
  const float* emb = (const float*)d_in[1];
  const float* w_ih = (const float*)d_in[2];
  const float* w_hh = (const float*)d_in[3];
  const float* b_ih = (const float*)d_in[4];
  const float* b_hh = (const float*)d_in[5];
  const float* gamma = (const float*)d_in[6];
  const float* beta = (const float*)d_in[7];
  const float* head_w = (const float*)d_in[8];
  const float* head_b = (const float*)d_in[9];
  float* out = (float*)d_out;

  char* ws = (char*)d_ws;
  size_t off = 0;
  auto alloc = [&](size_t bytes) -> void* {
    void* p = ws + off;
    off = (off + bytes + 255) & ~(size_t)255;
    return p;
  };
  int* ibase = (int*)alloc(1536 * sizeof(int));
  unsigned short* h_state = (unsigned short*)alloc(2 * 16 * HID * 2);
  unsigned short* A1 = (unsigned short*)alloc((size_t)NB * SEQ * HID * 2);
  unsigned short* wihb = (unsigned short*)alloc((size_t)NG * HID * 2);
  unsigned short* hwb = (unsigned short*)alloc((size_t)VOCAB * HID * 2);
  float* xg = (float*)alloc((size_t)NB * SEQ * NG * 4);
  float* hsb = (float*)alloc((size_t)NB * SEQ * HID * 4);
  unsigned short* yb = (unsigned short*)alloc((size_t)NB * SEQ * HID * 2);

  init_ws_kernel<<<64, 256, 0, stream>>>(ibase, h_state);
  conv_bf16_kernel<<<(NG * HID / 4) / 256, 256, 0, stream>>>(w_ih, wihb,
                                                             NG * HID / 4);
  conv_bf16_kernel<<<(VOCAB * HID / 4) / 256, 256, 0, stream>>>(
      head_w, hwb, VOCAB * HID / 4);
  embed_kernel<<<NB * SEQ, 256, 0, stream>>>(ids, emb, A1);
  // xg = A1 * w_ih^T + b_ih : M=4096, N=1536 (grid 384, %8==0)
  gemm_bt_kernel<<<(NB * SEQ / BM) * (NG / BN), 256, 0, stream>>>(
      A1, wihb, b_ih, xg, NG, NG / BN);
  // fused GRU + LN + head GEMM (32 GRU blocks + 224 workers)
  mega_kernel<<<GRU_WGS + NWRK, 256, 0, stream>>>(
      xg, w_hh, b_hh, hsb, h_state, ibase, hwb, head_b, gamma, beta, yb, out);
}

// Round 11
// 1691.881 us; speedup vs baseline: 1.2075x; 1.2075x over previous
//
#include <hip/hip_runtime.h>
#include <hip/hip_bf16.h>
#include <stdint.h>

#define VOCAB 32000
#define HID 512
#define NB 8
#define SEQ 512
#define NG 1536
#define LN_EPS 1e-5f
#define GRU_WGS 32
#define HEATERS 224
#define GRU_SPIN_BUDGET (1 << 20)

typedef short bf16x8 __attribute__((ext_vector_type(8)));
typedef float f32x4 __attribute__((ext_vector_type(4)));

__device__ __forceinline__ unsigned short f2bf(float f) {
  union { float f; uint32_t u; } c; c.f = f;
  return (unsigned short)((c.u + 0x7fffu + ((c.u >> 16) & 1u)) >> 16);
}

// ---------------- init workspace (every launch: h_state=0, flags=0) ---------
__global__ void init_ws_kernel(unsigned short* h_state, int* flags) {
  int i = blockIdx.x * 256 + threadIdx.x;
  if (i < 2 * 16 * HID) h_state[i] = 0;
  if (i < GRU_WGS * 16) flags[i] = 0;
}

// ---------------- fp32 -> bf16 bulk convert ---------------------------------
__global__ void conv_bf16_kernel(const float* __restrict__ in,
                                 unsigned short* __restrict__ out, int n4) {
  int i = blockIdx.x * 256 + threadIdx.x;
  if (i >= n4) return;
  const float4 v = ((const float4*)in)[i];
  ushort4 o;
  o.x = f2bf(v.x); o.y = f2bf(v.y); o.z = f2bf(v.z); o.w = f2bf(v.w);
  ((ushort4*)out)[i] = o;
}

// ---------------- embedding gather -> bf16 A matrix [4096][512] -------------
__global__ void embed_kernel(const int* __restrict__ ids,
                             const float* __restrict__ emb,
                             unsigned short* __restrict__ out) {
  int row = blockIdx.x;
  int id = ids[row];
  int c = threadIdx.x * 2;
  const float2 v = *(const float2*)(emb + (size_t)id * HID + c);
  ushort2 o; o.x = f2bf(v.x); o.y = f2bf(v.y);
  *(ushort2*)(out + (size_t)row * HID + c) = o;
}

// ---------------- bf16 GEMM: C[M][N] = A[M][K] * B[N][K]^T + bias -----------
#define BM 128
#define BN 128
#define BK 32

__global__ __launch_bounds__(256, 2) void gemm_bt_kernel(
    const unsigned short* __restrict__ A, const unsigned short* __restrict__ B,
    const float* __restrict__ bias, float* __restrict__ C, int N, int nbn) {
  __shared__ unsigned short a_lds[BM * BK];
  __shared__ unsigned short b_lds[BN * BK];
  const int nwg = gridDim.x;
  const int chunk = nwg >> 3;
  const int bid = blockIdx.x;
  const int sw = (bid & 7) * chunk + (bid >> 3);
  const int bm = sw / nbn, bn = sw % nbn;
  const int tid = threadIdx.x;
  const int lane = tid & 63, wid = tid >> 6;
  const int wm = wid >> 1, wn = wid & 1;

  f32x4 acc[4][4] = {};

  for (int kt = 0; kt < HID / BK; ++kt) {
    __syncthreads();
#pragma unroll
    for (int p = 0; p < 2; ++p) {
      const int flat = (p * 256 + tid) * 16;  // byte offset in 8KB tile
      const int row = flat >> 6;              // 64B per row (32 bf16)
      const int kb = flat & 63;
      const char* ga =
          (const char*)(A + ((size_t)(bm * BM + row) * HID + kt * BK)) + kb;
      const char* gb =
          (const char*)(B + ((size_t)(bn * BN + row) * HID + kt * BK)) + kb;
      char* la = (char*)a_lds + (size_t)(p * 256 + wid * 64) * 16;
      char* lb = (char*)b_lds + (size_t)(p * 256 + wid * 64) * 16;
      __builtin_amdgcn_global_load_lds(
          (const __attribute__((address_space(1))) void*)ga,
          (__attribute__((address_space(3))) void*)la, 16, 0, 0);
      __builtin_amdgcn_global_load_lds(
          (const __attribute__((address_space(1))) void*)gb,
          (__attribute__((address_space(3))) void*)lb, 16, 0, 0);
    }
    __syncthreads();
    bf16x8 af[4], bfr[4];
#pragma unroll
    for (int i = 0; i < 4; ++i) {
      af[i] = *(const bf16x8*)(a_lds + (wm * 64 + i * 16 + (lane & 15)) * BK +
                               (lane >> 4) * 8);
      bfr[i] = *(const bf16x8*)(b_lds + (wn * 64 + i * 16 + (lane & 15)) * BK +
                                (lane >> 4) * 8);
    }
#pragma unroll
    for (int i = 0; i < 4; ++i)
#pragma unroll
      for (int j = 0; j < 4; ++j)
        acc[i][j] =
            __builtin_amdgcn_mfma_f32_16x16x32_bf16(af[i], bfr[j], acc[i][j], 0, 0, 0);
  }
#pragma unroll
  for (int i = 0; i < 4; ++i) {
    const int mrow = bm * BM + wm * 64 + i * 16 + (lane >> 4) * 4;
#pragma unroll
    for (int j = 0; j < 4; ++j) {
      const int col = bn * BN + wn * 64 + j * 16 + (lane & 15);
      const float bv = bias[col];
#pragma unroll
      for (int r = 0; r < 4; ++r)
        C[(size_t)(mrow + r) * N + col] = acc[i][j][r] + bv;
    }
  }
}

// ---------------- persistent GRU scan + DPM heater blocks --------------------
// Blocks 0..31: round-5 GRU verbatim (1 wave/WG; flag protocol; all cross-WG
// traffic relaxed agent-scope = LLC, no cache maintenance). Best measured:
// 2.83 us/step.
// Blocks 32..255: pure-VALU heaters. Hypothesis under test: the GRU's serial
// LLC hop chain (~2100-2700 cy) is stretched ~2.5-3x by DPM downclocking at
// 0.4% occupancy. Heaters raise chip activity (register-only FMA, ZERO memory
// traffic except one broadcast flag poll every ~2048 FMA) so core+fabric hold
// high clock. Exit: flags[0] >= SEQ (always reached; GRU stores flags every
// step regardless of spin-budget state) or hard iteration cap.
__global__ __launch_bounds__(64, 1) void gru_kernel(
    const float* __restrict__ xg, const float* __restrict__ w_hh,
    const float* __restrict__ b_hh, float* __restrict__ hs,
    unsigned short* h_state, int* flags) {
  if (blockIdx.x >= GRU_WGS) {
    // ---- heater ----
    float a0 = (float)(threadIdx.x + 1) * 1.0000001f;
    float c0 = 0.f, c1 = 1.f, c2 = 2.f, c3 = 3.f;
    const float b = 0.9999999f;
    for (int it = 0; it < (1 << 14); ++it) {
#pragma unroll 64
      for (int i = 0; i < 512; ++i) {
        c0 = fmaf(c0, b, a0);
        c1 = fmaf(c1, b, a0);
        c2 = fmaf(c2, b, a0);
        c3 = fmaf(c3, b, a0);
      }
      asm volatile("" :: "v"(c0), "v"(c1), "v"(c2), "v"(c3));
      const int v = __hip_atomic_load(flags, __ATOMIC_RELAXED,
                                      __HIP_MEMORY_SCOPE_AGENT);
      if (v >= SEQ) break;
    }
    return;
  }

  const int wid = blockIdx.x;
  const int lane = threadIdx.x;
  const int col16 = lane & 15;
  const int kq = lane >> 4;  // 0..3 : which 8-wide K slice of the 32-window

  __shared__ float h_pub[8][16];

  // pack all 3 gates' weights into 48 MFMA B-fragments (registers), once
  bf16x8 wf[3][16];
#pragma unroll
  for (int g = 0; g < 3; ++g) {
    const float* wr =
        w_hh + (size_t)(g * HID + wid * 16 + col16) * HID + kq * 8;
#pragma unroll
    for (int kk = 0; kk < 16; ++kk) {
      float4 f0 = *(const float4*)(wr + kk * 32);
      float4 f1 = *(const float4*)(wr + kk * 32 + 4);
      bf16x8 v;
      v[0] = (short)f2bf(f0.x); v[1] = (short)f2bf(f0.y);
      v[2] = (short)f2bf(f0.z); v[3] = (short)f2bf(f0.w);
      v[4] = (short)f2bf(f1.x); v[5] = (short)f2bf(f1.y);
      v[6] = (short)f2bf(f1.z); v[7] = (short)f2bf(f1.w);
      wf[g][kk] = v;
    }
  }
  const float bh_r = b_hh[0 * HID + wid * 16 + col16];
  const float bh_z = b_hh[1 * HID + wid * 16 + col16];
  const float bh_n = b_hh[2 * HID + wid * 16 + col16];

  const int abase = col16 * HID + kq * 8;  // A-frag: row=batch=col16, k=kq*8
  const bool realrow = col16 < 8;          // batches 8..15 are padding zeros
  const bool owner = lane < 32;            // lanes 0..31 own real (batch,col)
  const int bbase = kq * 4;                // first batch of this lane's C rows

  // per-lane xg for 4 batches (prefetched); lanes>=32 unused
  float xr[4], xz[4], xn[4];
#pragma unroll
  for (int r = 0; r < 4; ++r) { xr[r] = 0.f; xz[r] = 0.f; xn[r] = 0.f; }
  if (owner) {
#pragma unroll
    for (int r = 0; r < 4; ++r) {
      const size_t xo = (size_t)(bbase + r) * SEQ * NG + wid * 16 + col16;
      xr[r] = xg[xo];
      xz[r] = xg[xo + HID];
      xn[r] = xg[xo + 2 * HID];
    }
  }
  float hprev[4] = {0.f, 0.f, 0.f, 0.f};
  int budget = GRU_SPIN_BUDGET;

  for (int t = 0; t < SEQ; ++t) {
    // ---- wait for h_t (flags >= t); all 64 lanes in the ballot ----
    while (budget > 0) {
      int v = t;
      if (lane < 32)
        v = __hip_atomic_load(flags + lane * 16, __ATOMIC_RELAXED,
                              __HIP_MEMORY_SCOPE_AGENT);
      if (__ballot(v >= t) == ~0ULL) break;
      --budget;
      __builtin_amdgcn_s_sleep(1);
    }

    const unsigned short* rd = h_state + (size_t)(t & 1) * (16 * HID);
    unsigned short* wpub = h_state + (size_t)((t + 1) & 1) * (16 * HID);

    // ---- bulk-load A fragments (one shot, all independent) ----
    uint64_t hb[32];
#pragma unroll
    for (int kk = 0; kk < 32; ++kk) hb[kk] = 0;
    if (realrow) {
#pragma unroll
      for (int kk = 0; kk < 16; ++kk) {
        const uint64_t* ap = (const uint64_t*)(rd + abase + kk * 32);
        hb[2 * kk] =
            __hip_atomic_load(ap, __ATOMIC_RELAXED, __HIP_MEMORY_SCOPE_AGENT);
        hb[2 * kk + 1] = __hip_atomic_load(ap + 1, __ATOMIC_RELAXED,
                                           __HIP_MEMORY_SCOPE_AGENT);
      }
    }

    // ---- three independent 16-deep MFMA chains (r, z, n) ----
    f32x4 ar = {0.f, 0.f, 0.f, 0.f};
    f32x4 az = {0.f, 0.f, 0.f, 0.f};
    f32x4 an = {0.f, 0.f, 0.f, 0.f};
#pragma unroll
    for (int kk = 0; kk < 16; ++kk) {
      union { uint64_t u[2]; bf16x8 v; } cv;
      cv.u[0] = hb[2 * kk]; cv.u[1] = hb[2 * kk + 1];
      ar = __builtin_amdgcn_mfma_f32_16x16x32_bf16(cv.v, wf[0][kk], ar, 0, 0, 0);
      az = __builtin_amdgcn_mfma_f32_16x16x32_bf16(cv.v, wf[1][kk], az, 0, 0, 0);
      an = __builtin_amdgcn_mfma_f32_16x16x32_bf16(cv.v, wf[2][kk], an, 0, 0, 0);
    }

    // ---- in-register gate math: lane owns (batch bbase+r, col col16) ----
    float hnew[4];
    if (owner) {
#pragma unroll
      for (int r = 0; r < 4; ++r) {
        const float rg = 1.f / (1.f + __expf(-(xr[r] + ar[r] + bh_r)));
        const float zg = 1.f / (1.f + __expf(-(xz[r] + az[r] + bh_z)));
        const float a = xn[r] + rg * (an[r] + bh_n);
        const float e2 = __expf(-2.f * fabsf(a));
        const float nn = copysignf((1.f - e2) / (1.f + e2), a);
        hnew[r] = (1.f - zg) * nn + zg * hprev[r];
        hprev[r] = hnew[r];
        h_pub[bbase + r][col16] = hnew[r];
      }
    }
    asm volatile("" ::: "memory");  // keep ds_writes before ds_reads
    // ---- barrier-free within-wave transpose + publish ----
    {
      const int tb = lane >> 3;          // batch 0..7
      const int tc = (lane & 7) * 2;     // even col of the pair
      const float2 hp = *(const float2*)&h_pub[tb][tc];
      union { unsigned short s[2]; uint32_t u; } pk;
      pk.s[0] = f2bf(hp.x);
      pk.s[1] = f2bf(hp.y);
      uint32_t* dst = (uint32_t*)(wpub + tb * HID + wid * 16 + tc);
      __hip_atomic_store(dst, pk.u, __ATOMIC_RELAXED,
                         __HIP_MEMORY_SCOPE_AGENT);
    }
    asm volatile("s_waitcnt vmcnt(0)" ::: "memory");  // drain publish stores
    if (lane == 0)
      __hip_atomic_store(flags + wid * 16, t + 1, __ATOMIC_RELAXED,
                         __HIP_MEMORY_SCOPE_AGENT);
    // ---- off-critical-path: hs output + next xg prefetch ----
    if (owner) {
#pragma unroll
      for (int r = 0; r < 4; ++r)
        hs[((size_t)(bbase + r) * SEQ + t) * HID + wid * 16 + col16] = hnew[r];
      if (t + 1 < SEQ) {
#pragma unroll
        for (int r = 0; r < 4; ++r) {
          const size_t xo = (size_t)(bbase + r) * SEQ * NG +
                            (size_t)(t + 1) * NG + wid * 16 + col16;
          xr[r] = xg[xo];
          xz[r] = xg[xo + HID];
          xn[r] = xg[xo + 2 * HID];
        }
      }
    }
  }
}

// ---------------- LayerNorm rows of 512 -> bf16 ------------------------------
__global__ __launch_bounds__(256) void ln_kernel(
    const float* __restrict__ hs, const float* __restrict__ gamma,
    const float* __restrict__ beta, unsigned short* __restrict__ y) {
  const int row = blockIdx.x * 4 + (threadIdx.x >> 6);
  const int lane = threadIdx.x & 63;
  const float* x = hs + (size_t)row * HID + lane * 8;
  float v[8];
  *(float4*)v = *(const float4*)x;
  *(float4*)(v + 4) = *(const float4*)(x + 4);
  float s = 0.f, q = 0.f;
#pragma unroll
  for (int j = 0; j < 8; ++j) { s += v[j]; q += v[j] * v[j]; }
#pragma unroll
  for (int off = 32; off > 0; off >>= 1) {
    s += __shfl_xor(s, off);
    q += __shfl_xor(q, off);
  }
  const float mu = s * (1.f / 512.f);
  const float is = rsqrtf(q * (1.f / 512.f) - mu * mu + LN_EPS);
  const float* gp = gamma + lane * 8;
  const float* bp = beta + lane * 8;
  union { unsigned short o[8]; uint4 u; } pk;
#pragma unroll
  for (int j = 0; j < 8; ++j) pk.o[j] = f2bf((v[j] - mu) * is * gp[j] + bp[j]);
  *(uint4*)(y + (size_t)row * HID + lane * 8) = pk.u;
}

// ---------------- launch -----------------------------------------------------
extern "C" void kernel_launch(void* const* d_in, const int* in_sizes, int n_in,
                              void* d_out, int out_size, void* d_ws,
                              size_t ws_size, hipStream_t stream) {
  const int* ids = (const int*)d_in[0];
  const float* emb = (const float*)d_in[1];
  const float* w_ih = (const float*)d_in[2];
  const float* w_hh = (const float*)d_in[3];
  const float* b_ih = (const float*)d_in[4];
  const float* b_hh = (const float*)d_in[5];
  const float* gamma = (const float*)d_in[6];
  const float* beta = (const float*)d_in[7];
  const float* head_w = (const float*)d_in[8];
  const float* head_b = (const float*)d_in[9];
  float* out = (float*)d_out;

  char* ws = (char*)d_ws;
  size_t off = 0;
  auto alloc = [&](size_t bytes) -> void* {
    void* p = ws + off;
    off = (off + bytes + 255) & ~(size_t)255;
    return p;
  };
  int* flags = (int*)alloc(GRU_WGS * 16 * sizeof(int));
  unsigned short* h_state = (unsigned short*)alloc(2 * 16 * HID * 2);
  unsigned short* A1 = (unsigned short*)alloc((size_t)NB * SEQ * HID * 2);
  unsigned short* wihb = (unsigned short*)alloc((size_t)NG * HID * 2);
  unsigned short* hwb = (unsigned short*)alloc((size_t)VOCAB * HID * 2);
  float* xg = (float*)alloc((size_t)NB * SEQ * NG * 4);
  float* hsb = (float*)alloc((size_t)NB * SEQ * HID * 4);
  unsigned short* yb = (unsigned short*)alloc((size_t)NB * SEQ * HID * 2);

  init_ws_kernel<<<64, 256, 0, stream>>>(h_state, flags);
  conv_bf16_kernel<<<(NG * HID / 4) / 256, 256, 0, stream>>>(w_ih, wihb,
                                                             NG * HID / 4);
  conv_bf16_kernel<<<(VOCAB * HID / 4) / 256, 256, 0, stream>>>(
      head_w, hwb, VOCAB * HID / 4);
  embed_kernel<<<NB * SEQ, 256, 0, stream>>>(ids, emb, A1);
  // xg = A1 * w_ih^T + b_ih : M=4096, N=1536  (grid 32*12=384, %8==0)
  gemm_bt_kernel<<<(NB * SEQ / BM) * (NG / BN), 256, 0, stream>>>(
      A1, wihb, b_ih, xg, NG, NG / BN);
  // GRU (blocks 0..31) + DPM heaters (blocks 32..255)
  gru_kernel<<<GRU_WGS + HEATERS, 64, 0, stream>>>(xg, w_hh, b_hh, hsb,
                                                   h_state, flags);
  ln_kernel<<<NB * SEQ / 4, 256, 0, stream>>>(hsb, gamma, beta, yb);
  // logits = y * head_w^T + head_b : M=4096, N=32000 (grid 32*250=8000, %8==0)
  gemm_bt_kernel<<<(NB * SEQ / BM) * (VOCAB / BN), 256, 0, stream>>>(
      yb, hwb, head_b, out, VOCAB, VOCAB / BN);
}